// Round 2
// baseline (34210.141 us; speedup 1.0000x reference)
//
#include <hip/hip_runtime.h>
#include <math.h>

#define Bsz 64
#define Tn 64
#define Ln 100
#define Dn 128
#define An 18
#define Hn 512

__device__ __forceinline__ float sigf(float x){ return 1.0f/(1.0f+expf(-x)); }

// ---- device-scope grid barrier (all blocks co-resident; agent-scope fences
// give cross-XCD visibility: release -> wbL2, acquire -> invL2) ----
__device__ __forceinline__ void gbar(int* cnt, int* gen, int nb){
  __syncthreads();
  if (threadIdx.x == 0){
    int g = __hip_atomic_load(gen, __ATOMIC_RELAXED, __HIP_MEMORY_SCOPE_AGENT);
    int a = __hip_atomic_fetch_add(cnt, 1, __ATOMIC_ACQ_REL, __HIP_MEMORY_SCOPE_AGENT);
    if (a == nb - 1){
      __hip_atomic_store(cnt, 0, __ATOMIC_RELAXED, __HIP_MEMORY_SCOPE_AGENT);
      __hip_atomic_fetch_add(gen, 1, __ATOMIC_RELEASE, __HIP_MEMORY_SCOPE_AGENT);
    } else {
      while (__hip_atomic_load(gen, __ATOMIC_ACQUIRE, __HIP_MEMORY_SCOPE_AGENT) == g)
        __builtin_amdgcn_s_sleep(1);
    }
  }
  __syncthreads();
}

// ---------- demo transpose: demoT[l][d][b] = demo[0][b][l][d] ----------
__global__ __launch_bounds__(256) void demo_transpose_kernel(
    const float* __restrict__ demo, float* __restrict__ demoT)
{
  int idx = blockIdx.x*256 + threadIdx.x;
  if (idx < Ln*Dn*Bsz) {
    int b = idx & 63;
    int d = (idx >> 6) & 127;
    int l = idx >> 13;
    demoT[idx] = demo[((size_t)(b*Ln + l))*Dn + d];
  }
}

// ---------- generic tiled GEMM: C[M][N] = A[M][K] * B[N][K]^T + bias[n] ----------
__global__ __launch_bounds__(256) void gemm_nt_kernel(
    const float* __restrict__ A, int lda,
    const float* __restrict__ B, int ldb,
    const float* __restrict__ bias,
    float* __restrict__ C, int ldc, int K)
{
  __shared__ float As[64][17];
  __shared__ float Bs[64][17];
  const int m0 = blockIdx.x * 64;
  const int n0 = blockIdx.y * 64;
  const int tx = threadIdx.x & 15;
  const int ty = threadIdx.x >> 4;
  float acc[4][4] = {};
  for (int k0 = 0; k0 < K; k0 += 16) {
    #pragma unroll
    for (int i = 0; i < 4; i++) {
      int e = threadIdx.x + i*256;
      int r = e >> 4, c = e & 15;
      As[r][c] = A[(size_t)(m0 + r)*lda + k0 + c];
      Bs[r][c] = B[(size_t)(n0 + r)*ldb + k0 + c];
    }
    __syncthreads();
    #pragma unroll
    for (int kk = 0; kk < 16; kk++) {
      float a0 = As[ty*4+0][kk], a1 = As[ty*4+1][kk], a2 = As[ty*4+2][kk], a3 = As[ty*4+3][kk];
      float b0 = Bs[tx*4+0][kk], b1 = Bs[tx*4+1][kk], b2 = Bs[tx*4+2][kk], b3 = Bs[tx*4+3][kk];
      acc[0][0] += a0*b0; acc[0][1] += a0*b1; acc[0][2] += a0*b2; acc[0][3] += a0*b3;
      acc[1][0] += a1*b0; acc[1][1] += a1*b1; acc[1][2] += a1*b2; acc[1][3] += a1*b3;
      acc[2][0] += a2*b0; acc[2][1] += a2*b1; acc[2][2] += a2*b2; acc[2][3] += a2*b3;
      acc[3][0] += a3*b0; acc[3][1] += a3*b1; acc[3][2] += a3*b2; acc[3][3] += a3*b3;
    }
    __syncthreads();
  }
  #pragma unroll
  for (int i = 0; i < 4; i++) {
    #pragma unroll
    for (int j = 0; j < 4; j++) {
      int nn = n0 + tx*4 + j;
      float v = acc[i][j] + (bias ? bias[nn] : 0.0f);
      C[(size_t)(m0 + ty*4 + i)*ldc + nn] = v;
    }
  }
}

// ---------- persistent encoder scan: 512 blocks, 100 steps, grid barrier ----------
__global__ __launch_bounds__(256, 2) void enc_scan_kernel(
    const float* __restrict__ demoT,   // [Ln][Dn][Bsz]
    const float* __restrict__ Wih, const float* __restrict__ Whh,
    const float* __restrict__ bih, const float* __restrict__ bhh,
    float* __restrict__ henc,          // 2 x [Hn][Bsz]
    float* __restrict__ enc,           // [Bsz][Ln][Hn]
    int* __restrict__ bar)
{
  const int n    = blockIdx.x;
  const int lane = threadIdx.x & 63;
  const int ks   = threadIdx.x >> 6;
  const int r0 = n, r1 = Hn + n, r2 = 2*Hn + n, r3 = 3*Hn + n;

  const float4* wh0 = (const float4*)(Whh + (size_t)r0*Hn) + ks*32;
  const float4* wh1 = (const float4*)(Whh + (size_t)r1*Hn) + ks*32;
  const float4* wh2 = (const float4*)(Whh + (size_t)r2*Hn) + ks*32;
  const float4* wh3 = (const float4*)(Whh + (size_t)r3*Hn) + ks*32;
  const float4* wi0 = (const float4*)(Wih + (size_t)r0*Dn) + ks*8;
  const float4* wi1 = (const float4*)(Wih + (size_t)r1*Dn) + ks*8;
  const float4* wi2 = (const float4*)(Wih + (size_t)r2*Dn) + ks*8;
  const float4* wi3 = (const float4*)(Wih + (size_t)r3*Dn) + ks*8;

  const float bs0 = bih[r0] + bhh[r0];
  const float bs1 = bih[r1] + bhh[r1];
  const float bs2 = bih[r2] + bhh[r2];
  const float bs3 = bih[r3] + bhh[r3];

  float creg = 0.0f;   // cell state for (column n, batch lane) held by tid<64
  __shared__ float red[4][4][Bsz];

  for (int l = 0; l < Ln; l++) {
    float a0 = 0.f, a1 = 0.f, a2 = 0.f, a3 = 0.f;
    if (l > 0) {
      const float* hp = henc + ((l & 1) ^ 1)*(Hn*Bsz) + ks*128*Bsz + lane;
      #pragma unroll 4
      for (int q = 0; q < 32; q++) {
        float4 W0 = wh0[q], W1 = wh1[q], W2 = wh2[q], W3 = wh3[q];
        float v0 = hp[(4*q+0)*Bsz], v1 = hp[(4*q+1)*Bsz];
        float v2 = hp[(4*q+2)*Bsz], v3 = hp[(4*q+3)*Bsz];
        a0 += v0*W0.x + v1*W0.y + v2*W0.z + v3*W0.w;
        a1 += v0*W1.x + v1*W1.y + v2*W1.z + v3*W1.w;
        a2 += v0*W2.x + v1*W2.y + v2*W2.z + v3*W2.w;
        a3 += v0*W3.x + v1*W3.y + v2*W3.z + v3*W3.w;
      }
    }
    {
      const float* dp = demoT + ((size_t)l*Dn + ks*32)*Bsz + lane;
      #pragma unroll
      for (int q = 0; q < 8; q++) {
        float4 W0 = wi0[q], W1 = wi1[q], W2 = wi2[q], W3 = wi3[q];
        float v0 = dp[(4*q+0)*Bsz], v1 = dp[(4*q+1)*Bsz];
        float v2 = dp[(4*q+2)*Bsz], v3 = dp[(4*q+3)*Bsz];
        a0 += v0*W0.x + v1*W0.y + v2*W0.z + v3*W0.w;
        a1 += v0*W1.x + v1*W1.y + v2*W1.z + v3*W1.w;
        a2 += v0*W2.x + v1*W2.y + v2*W2.z + v3*W2.w;
        a3 += v0*W3.x + v1*W3.y + v2*W3.z + v3*W3.w;
      }
    }
    red[ks][0][lane] = a0; red[ks][1][lane] = a1;
    red[ks][2][lane] = a2; red[ks][3][lane] = a3;
    __syncthreads();
    if (threadIdx.x < Bsz) {
      int b = threadIdx.x;
      float g0 = red[0][0][b]+red[1][0][b]+red[2][0][b]+red[3][0][b] + bs0;
      float g1 = red[0][1][b]+red[1][1][b]+red[2][1][b]+red[3][1][b] + bs1;
      float g2 = red[0][2][b]+red[1][2][b]+red[2][2][b]+red[3][2][b] + bs2;
      float g3 = red[0][3][b]+red[1][3][b]+red[2][3][b]+red[3][3][b] + bs3;
      float ii = sigf(g0), ff = sigf(g1), gg = tanhf(g2), oo = sigf(g3);
      float cn = ff*creg + ii*gg;
      float hn = oo*tanhf(cn);
      creg = cn;
      henc[(l & 1)*(Hn*Bsz) + n*Bsz + b] = hn;
      enc[((size_t)b*Ln + l)*Hn + n] = hn;
    }
    gbar(bar + 0, bar + 1, (int)gridDim.x);
  }
}

// ---------- persistent decoder scan: 576 blocks (64 attn + 512 col), 64 steps ----------
__global__ __launch_bounds__(256, 3) void dec_scan_kernel(
    const float* __restrict__ h0, const float* __restrict__ c0,
    const float* __restrict__ attnp,   // [Bsz*Ln][Hn]
    const float* __restrict__ enc,     // [Bsz][Ln][Hn]
    const int*   __restrict__ dlen,
    const float* __restrict__ lstm_Wih, const float* __restrict__ lstm_Whh,
    const float* __restrict__ lstm_bih, const float* __restrict__ lstm_bhh,
    const float* __restrict__ comb_W,  const float* __restrict__ comb_b,
    const float* __restrict__ preobsT, // [Hn][Tn*Bsz]
    float* __restrict__ hT,            // 2 x [Hn][Bsz]
    float* __restrict__ appT,          // [Hn][Bsz]
    float* __restrict__ hpart,         // [4Hn][Bsz]
    float* __restrict__ xT,            // [Hn][Bsz]
    float* __restrict__ hhist,         // [Tn][Bsz][Hn]
    float* __restrict__ outp,          // d_out (float)
    int* __restrict__ bar)
{
  const int bid  = blockIdx.x;
  const int tid  = threadIdx.x;
  const int lane = tid & 63;
  const int ks   = tid >> 6;

  __shared__ float hs[Hn];
  __shared__ float wls[128];
  __shared__ float mx_s, sum_s;
  __shared__ float red[4][4][Bsz];

  // ---- phase-A hpart role constants (bid in [64,576)) ----
  const int na = bid - 64;
  const float4* wa0 = (const float4*)(lstm_Whh + (size_t)(na)        *Hn) + ks*32;
  const float4* wa1 = (const float4*)(lstm_Whh + (size_t)(Hn   + na) *Hn) + ks*32;
  const float4* wa2 = (const float4*)(lstm_Whh + (size_t)(2*Hn + na) *Hn) + ks*32;
  const float4* wa3 = (const float4*)(lstm_Whh + (size_t)(3*Hn + na) *Hn) + ks*32;

  // ---- phase-B/C role constants (bid in [0,512)) ----
  const float4* wc  = (const float4*)(comb_W + (size_t)bid*(Hn + Dn)) + ks*32;
  const float4* wg0 = (const float4*)(lstm_Wih + (size_t)(bid)        *Hn) + ks*32;
  const float4* wg1 = (const float4*)(lstm_Wih + (size_t)(Hn   + bid) *Hn) + ks*32;
  const float4* wg2 = (const float4*)(lstm_Wih + (size_t)(2*Hn + bid) *Hn) + ks*32;
  const float4* wg3 = (const float4*)(lstm_Wih + (size_t)(3*Hn + bid) *Hn) + ks*32;
  float bsum0 = 0.f, bsum1 = 0.f, bsum2 = 0.f, bsum3 = 0.f, cb = 0.f;
  if (bid < 512) {
    bsum0 = lstm_bih[bid]        + lstm_bhh[bid];
    bsum1 = lstm_bih[Hn + bid]   + lstm_bhh[Hn + bid];
    bsum2 = lstm_bih[2*Hn + bid] + lstm_bhh[2*Hn + bid];
    bsum3 = lstm_bih[3*Hn + bid] + lstm_bhh[3*Hn + bid];
    cb = comb_b[bid];
  }
  float creg = 0.0f;

  for (int t = 0; t < Tn; t++) {
    // ================= Phase A =================
    if (bid < 64) {
      // attention for batch b = bid
      const int b = bid;
      const float* hrow = (t == 0) ? (h0 + (size_t)b*Hn)
                                   : (hhist + ((size_t)(t-1)*Bsz + b)*Hn);
      for (int i = tid; i < Hn; i += 256) hs[i] = hrow[i];
      if (tid >= 200 && tid < 228) wls[tid - 100] = -1e30f;
      __syncthreads();
      const int len = dlen[b];
      if (tid < 200) {
        int l = tid >> 1, kh = tid & 1;
        const float* ap = attnp + ((size_t)(b*Ln + l))*Hn + kh*256;
        const float* hh = hs + kh*256;
        float s = 0.f;
        #pragma unroll 8
        for (int k = 0; k < 256; k++) s += ap[k]*hh[k];
        s += __shfl_xor(s, 1);
        if (kh == 0) wls[l] = (l < len) ? s*0.1f : -1e30f;
      }
      __syncthreads();
      if (tid < 64) {
        float v = fmaxf(wls[tid], wls[tid+64]);
        for (int off = 1; off < 64; off <<= 1) v = fmaxf(v, __shfl_xor(v, off));
        if (tid == 0) mx_s = v;
      }
      __syncthreads();
      float mx = mx_s;
      if (tid < 64) {
        float e0 = (wls[tid]    > -1e29f) ? expf(wls[tid]    - mx) : 0.f;
        float e1 = (wls[tid+64] > -1e29f) ? expf(wls[tid+64] - mx) : 0.f;
        wls[tid] = e0; wls[tid+64] = e1;
        float v = e0 + e1;
        for (int off = 1; off < 64; off <<= 1) v += __shfl_xor(v, off);
        if (tid == 0) sum_s = v;
      }
      __syncthreads();
      float inv = 1.0f / sum_s;
      for (int c2 = 0; c2 < 2; c2++) {
        int hc = tid + c2*256;
        const float* eb = enc + (size_t)b*Ln*Hn + hc;
        float a = 0.f;
        for (int l2 = 0; l2 < len; ++l2) a += wls[l2]*eb[(size_t)l2*Hn];
        appT[hc*Bsz + b] = a*inv;
      }
    } else {
      // hpart = lstm_Whh @ h_{t-1} for column na
      float a0 = 0.f, a1 = 0.f, a2 = 0.f, a3 = 0.f;
      if (t == 0) {
        const float4* hv = (const float4*)(h0 + (size_t)lane*Hn) + ks*32;
        #pragma unroll 4
        for (int q = 0; q < 32; q++) {
          float4 V = hv[q];
          float4 W0 = wa0[q], W1 = wa1[q], W2 = wa2[q], W3 = wa3[q];
          a0 += V.x*W0.x + V.y*W0.y + V.z*W0.z + V.w*W0.w;
          a1 += V.x*W1.x + V.y*W1.y + V.z*W1.z + V.w*W1.w;
          a2 += V.x*W2.x + V.y*W2.y + V.z*W2.z + V.w*W2.w;
          a3 += V.x*W3.x + V.y*W3.y + V.z*W3.z + V.w*W3.w;
        }
      } else {
        const float* hp = hT + ((t & 1) ^ 1)*(Hn*Bsz) + ks*128*Bsz + lane;
        #pragma unroll 4
        for (int q = 0; q < 32; q++) {
          float4 W0 = wa0[q], W1 = wa1[q], W2 = wa2[q], W3 = wa3[q];
          float v0 = hp[(4*q+0)*Bsz], v1 = hp[(4*q+1)*Bsz];
          float v2 = hp[(4*q+2)*Bsz], v3 = hp[(4*q+3)*Bsz];
          a0 += v0*W0.x + v1*W0.y + v2*W0.z + v3*W0.w;
          a1 += v0*W1.x + v1*W1.y + v2*W1.z + v3*W1.w;
          a2 += v0*W2.x + v1*W2.y + v2*W2.z + v3*W2.w;
          a3 += v0*W3.x + v1*W3.y + v2*W3.z + v3*W3.w;
        }
      }
      red[ks][0][lane] = a0; red[ks][1][lane] = a1;
      red[ks][2][lane] = a2; red[ks][3][lane] = a3;
      __syncthreads();
      if (tid < Bsz) {
        int b = tid;
        hpart[(size_t)(na)       *Bsz + b] = red[0][0][b]+red[1][0][b]+red[2][0][b]+red[3][0][b];
        hpart[(size_t)(Hn+na)    *Bsz + b] = red[0][1][b]+red[1][1][b]+red[2][1][b]+red[3][1][b];
        hpart[(size_t)(2*Hn+na)  *Bsz + b] = red[0][2][b]+red[1][2][b]+red[2][2][b]+red[3][2][b];
        hpart[(size_t)(3*Hn+na)  *Bsz + b] = red[0][3][b]+red[1][3][b]+red[2][3][b]+red[3][3][b];
      }
    }
    gbar(bar + 2, bar + 3, (int)gridDim.x);

    // ================= Phase B: x = relu(Wh@applied + preobs + comb_b) =================
    if (bid < 512) {
      float a = 0.f;
      const float* ap = appT + ks*128*Bsz + lane;
      #pragma unroll 4
      for (int q = 0; q < 32; q++) {
        float4 W = wc[q];
        float v0 = ap[(4*q+0)*Bsz], v1 = ap[(4*q+1)*Bsz];
        float v2 = ap[(4*q+2)*Bsz], v3 = ap[(4*q+3)*Bsz];
        a += v0*W.x + v1*W.y + v2*W.z + v3*W.w;
      }
      red[ks][0][lane] = a;
      __syncthreads();
      if (tid < Bsz) {
        int b = tid;
        float v = red[0][0][b]+red[1][0][b]+red[2][0][b]+red[3][0][b];
        v += preobsT[(size_t)bid*(Tn*Bsz) + t*Bsz + b] + cb;
        xT[bid*Bsz + b] = fmaxf(v, 0.f);
      }
    }
    gbar(bar + 2, bar + 3, (int)gridDim.x);

    // ================= Phase C: gates -> cell -> h_t =================
    if (bid < 512) {
      float a0 = 0.f, a1 = 0.f, a2 = 0.f, a3 = 0.f;
      const float* xp = xT + ks*128*Bsz + lane;
      #pragma unroll 4
      for (int q = 0; q < 32; q++) {
        float4 W0 = wg0[q], W1 = wg1[q], W2 = wg2[q], W3 = wg3[q];
        float v0 = xp[(4*q+0)*Bsz], v1 = xp[(4*q+1)*Bsz];
        float v2 = xp[(4*q+2)*Bsz], v3 = xp[(4*q+3)*Bsz];
        a0 += v0*W0.x + v1*W0.y + v2*W0.z + v3*W0.w;
        a1 += v0*W1.x + v1*W1.y + v2*W1.z + v3*W1.w;
        a2 += v0*W2.x + v1*W2.y + v2*W2.z + v3*W2.w;
        a3 += v0*W3.x + v1*W3.y + v2*W3.z + v3*W3.w;
      }
      red[ks][0][lane] = a0; red[ks][1][lane] = a1;
      red[ks][2][lane] = a2; red[ks][3][lane] = a3;
      __syncthreads();
      if (tid < Bsz) {
        int b = tid;
        if (t == 0) creg = c0[(size_t)b*Hn + bid];
        float g0 = red[0][0][b]+red[1][0][b]+red[2][0][b]+red[3][0][b] + hpart[(size_t)(bid)     *Bsz+b] + bsum0;
        float g1 = red[0][1][b]+red[1][1][b]+red[2][1][b]+red[3][1][b] + hpart[(size_t)(Hn+bid)  *Bsz+b] + bsum1;
        float g2 = red[0][2][b]+red[1][2][b]+red[2][2][b]+red[3][2][b] + hpart[(size_t)(2*Hn+bid)*Bsz+b] + bsum2;
        float g3 = red[0][3][b]+red[1][3][b]+red[2][3][b]+red[3][3][b] + hpart[(size_t)(3*Hn+bid)*Bsz+b] + bsum3;
        float ii = sigf(g0), ff = sigf(g1), gg = tanhf(g2), oo = sigf(g3);
        float cn = ff*creg + ii*gg;
        float hn = oo*tanhf(cn);
        creg = cn;
        hT[(t & 1)*(Hn*Bsz) + bid*Bsz + b] = hn;
        hhist[((size_t)t*Bsz + b)*Hn + bid] = hn;
        if (t == Tn - 1) {
          outp[Tn*Bsz*An + (size_t)b*Hn + bid]            = hn;
          outp[Tn*Bsz*An + Bsz*Hn + (size_t)b*Hn + bid]   = cn;
        }
      }
    }
    gbar(bar + 2, bar + 3, (int)gridDim.x);
  }
}

// ---------- q head ----------
__global__ __launch_bounds__(256) void qout_kernel(
    const float* __restrict__ m, const float* __restrict__ out_W,
    const float* __restrict__ out_b, float* __restrict__ q)
{
  const int t = blockIdx.x;
  for (int p = threadIdx.x; p < Bsz*An; p += 256) {
    int b = p / An, a2 = p % An;
    const float* mr = m + ((size_t)(t*Bsz + b))*Hn;
    const float* wr = out_W + (size_t)a2*Hn;
    float s = out_b[a2];
    #pragma unroll 8
    for (int k = 0; k < Hn; k++) s += mr[k]*wr[k];
    q[((size_t)(t*Bsz + b))*An + a2] = s;
  }
}

extern "C" void kernel_launch(void* const* d_in, const int* in_sizes, int n_in,
                              void* d_out, int out_size, void* d_ws, size_t ws_size,
                              hipStream_t stream) {
  (void)in_sizes; (void)n_in; (void)out_size; (void)ws_size;
  const float* state    = (const float*)d_in[0];
  const float* demo     = (const float*)d_in[1];
  const int*   dlen     = (const int*)  d_in[2];
  const float* h0       = (const float*)d_in[5];
  const float* c0       = (const float*)d_in[6];
  const float* enc_Wih  = (const float*)d_in[7];
  const float* enc_Whh  = (const float*)d_in[8];
  const float* enc_bih  = (const float*)d_in[9];
  const float* enc_bhh  = (const float*)d_in[10];
  const float* attn_W   = (const float*)d_in[11];
  const float* attn_b   = (const float*)d_in[12];
  const float* comb_W   = (const float*)d_in[13];
  const float* comb_b   = (const float*)d_in[14];
  const float* lstm_Wih = (const float*)d_in[15];
  const float* lstm_Whh = (const float*)d_in[16];
  const float* lstm_bih = (const float*)d_in[17];
  const float* lstm_bhh = (const float*)d_in[18];
  const float* mid_W    = (const float*)d_in[19];
  const float* mid_b    = (const float*)d_in[20];
  const float* out_W    = (const float*)d_in[21];
  const float* out_b    = (const float*)d_in[22];
  float* ws   = (float*)d_ws;
  float* qout = (float*)d_out;

  // workspace layout (floats)
  float* demoT   = ws + 0;        // 819200
  float* henc    = ws + 819200;   // 65536
  float* enc     = ws + 884736;   // 3276800
  float* attnp   = ws + 4161536;  // 3276800
  float* preobsT = ws + 7438336;  // 2097152  [Hn][Tn*Bsz]
  float* hT      = ws + 9535488;  // 65536
  float* appT    = ws + 9601024;  // 32768
  float* hpart   = ws + 9633792;  // 131072
  float* xT      = ws + 9764864;  // 32768
  float* hhist   = ws + 9797632;  // 2097152
  int*   bar     = (int*)(ws + 11894784); // 4 ints
  float* mbuf    = enc;           // alias: enc dead after decoder

  hipMemsetAsync((void*)bar, 0, 16, stream);

  demo_transpose_kernel<<<3200, 256, 0, stream>>>(demo, demoT);

  // preobsT[n][t*B+b] = comb_W[n, 512:640] . state[t,b,:]   (transposed output)
  gemm_nt_kernel<<<dim3(Hn/64, Tn*Bsz/64), 256, 0, stream>>>(
      comb_W + Hn, Hn + Dn, state, Dn, nullptr, preobsT, Tn*Bsz, Dn);

  enc_scan_kernel<<<Hn, 256, 0, stream>>>(
      demoT, enc_Wih, enc_Whh, enc_bih, enc_bhh, henc, enc, bar);

  // attn_proj = enc @ attn_W^T + attn_b
  gemm_nt_kernel<<<dim3(Bsz*Ln/64, Hn/64), 256, 0, stream>>>(
      enc, Hn, attn_W, Hn, attn_b, attnp, Hn, Hn);

  dec_scan_kernel<<<Bsz + Hn, 256, 0, stream>>>(
      h0, c0, attnp, enc, dlen, lstm_Wih, lstm_Whh, lstm_bih, lstm_bhh,
      comb_W, comb_b, preobsT, hT, appT, hpart, xT, hhist, qout, bar);

  // m = hhist @ mid_W^T + mid_b
  gemm_nt_kernel<<<dim3(Tn*Bsz/64, Hn/64), 256, 0, stream>>>(
      hhist, Hn, mid_W, Hn, mid_b, mbuf, Hn, Hn);

  qout_kernel<<<Tn, 256, 0, stream>>>(mbuf, out_W, out_b, qout);
}

// Round 3
// 6879.951 us; speedup vs baseline: 4.9724x; 4.9724x over previous
//
#include <hip/hip_runtime.h>
#include <math.h>

#define Bsz 64
#define Tn 64
#define Ln 100
#define Dn 128
#define An 18
#define Hn 512

__device__ __forceinline__ float sigf(float x){ return 1.0f/(1.0f+expf(-x)); }

// write-through agent-scope store (no dirty L2 line; lands at coherence point)
__device__ __forceinline__ void scst(float* p, float v){
  __hip_atomic_store(p, v, __ATOMIC_RELAXED, __HIP_MEMORY_SCOPE_AGENT);
}

// grid barrier: relaxed bypass atomics for arrive/spin, ONE acquire fence at exit.
__device__ __forceinline__ void gbar(int* arrive, int* gen, int nb, int ph){
  __syncthreads();
  if (threadIdx.x == 0){
    asm volatile("s_waitcnt vmcnt(0) lgkmcnt(0)" ::: "memory");
    int a = __hip_atomic_fetch_add(arrive, 1, __ATOMIC_RELAXED, __HIP_MEMORY_SCOPE_AGENT) + 1;
    if (a == nb*ph){
      __hip_atomic_store(gen, ph, __ATOMIC_RELAXED, __HIP_MEMORY_SCOPE_AGENT);
    } else {
      while (__hip_atomic_load(gen, __ATOMIC_RELAXED, __HIP_MEMORY_SCOPE_AGENT) < ph)
        __builtin_amdgcn_s_sleep(4);
    }
    __builtin_amdgcn_fence(__ATOMIC_ACQUIRE, "agent");
  }
  __syncthreads();
}

// ---------- demo transpose: demoT[l][d][b] = demo[0][b][l][d] ----------
__global__ __launch_bounds__(256) void demo_transpose_kernel(
    const float* __restrict__ demo, float* __restrict__ demoT)
{
  int idx = blockIdx.x*256 + threadIdx.x;
  if (idx < Ln*Dn*Bsz) {
    int b = idx & 63;
    int d = (idx >> 6) & 127;
    int l = idx >> 13;
    demoT[idx] = demo[((size_t)(b*Ln + l))*Dn + d];
  }
}

// ---------- generic tiled GEMM: C[M][N] = A[M][K] * B[N][K]^T + bias[n] ----------
__global__ __launch_bounds__(256) void gemm_nt_kernel(
    const float* __restrict__ A, int lda,
    const float* __restrict__ B, int ldb,
    const float* __restrict__ bias,
    float* __restrict__ C, int ldc, int K)
{
  __shared__ float As[64][17];
  __shared__ float Bs[64][17];
  const int m0 = blockIdx.x * 64;
  const int n0 = blockIdx.y * 64;
  const int tx = threadIdx.x & 15;
  const int ty = threadIdx.x >> 4;
  float acc[4][4] = {};
  for (int k0 = 0; k0 < K; k0 += 16) {
    #pragma unroll
    for (int i = 0; i < 4; i++) {
      int e = threadIdx.x + i*256;
      int r = e >> 4, c = e & 15;
      As[r][c] = A[(size_t)(m0 + r)*lda + k0 + c];
      Bs[r][c] = B[(size_t)(n0 + r)*ldb + k0 + c];
    }
    __syncthreads();
    #pragma unroll
    for (int kk = 0; kk < 16; kk++) {
      float a0 = As[ty*4+0][kk], a1 = As[ty*4+1][kk], a2 = As[ty*4+2][kk], a3 = As[ty*4+3][kk];
      float b0 = Bs[tx*4+0][kk], b1 = Bs[tx*4+1][kk], b2 = Bs[tx*4+2][kk], b3 = Bs[tx*4+3][kk];
      acc[0][0] += a0*b0; acc[0][1] += a0*b1; acc[0][2] += a0*b2; acc[0][3] += a0*b3;
      acc[1][0] += a1*b0; acc[1][1] += a1*b1; acc[1][2] += a1*b2; acc[1][3] += a1*b3;
      acc[2][0] += a2*b0; acc[2][1] += a2*b1; acc[2][2] += a2*b2; acc[2][3] += a2*b3;
      acc[3][0] += a3*b0; acc[3][1] += a3*b1; acc[3][2] += a3*b2; acc[3][3] += a3*b3;
    }
    __syncthreads();
  }
  #pragma unroll
  for (int i = 0; i < 4; i++) {
    #pragma unroll
    for (int j = 0; j < 4; j++) {
      int nn = n0 + tx*4 + j;
      float v = acc[i][j] + (bias ? bias[nn] : 0.0f);
      C[(size_t)(m0 + ty*4 + i)*ldc + nn] = v;
    }
  }
}

// ---------- persistent fused encoder: h-scan + attnp + CE, 256 blocks x 2 cols ----------
__global__ __launch_bounds__(256, 1) void enc_scan_kernel(
    const float* __restrict__ demoT,   // [Ln][Dn][Bsz]
    const float* __restrict__ Wih, const float* __restrict__ Whh,
    const float* __restrict__ bih, const float* __restrict__ bhh,
    const float* __restrict__ attn_W, const float* __restrict__ attn_b,
    const float* __restrict__ comb_W,
    float* __restrict__ henc,          // 2 x [Hn][Bsz]
    float* __restrict__ attnp,         // [Bsz*Ln][Hn]
    float* __restrict__ CE,            // [Bsz*Hn][Ln]
    int* __restrict__ bar)
{
  const int bid  = blockIdx.x;
  const int lane = threadIdx.x & 63;
  const int ks   = threadIdx.x >> 6;
  const int n0 = bid*2;

  const float4* whh[8]; const float4* wih[8];
  #pragma unroll
  for (int c = 0; c < 2; c++)
    #pragma unroll
    for (int g = 0; g < 4; g++){
      int r = g*Hn + n0 + c;
      whh[c*4+g] = (const float4*)(Whh + (size_t)r*Hn) + ks*32;
      wih[c*4+g] = (const float4*)(Wih + (size_t)r*Dn) + ks*8;
    }
  const float4* atw[2] = {
    (const float4*)(attn_W + (size_t)(n0+0)*Hn) + ks*32,
    (const float4*)(attn_W + (size_t)(n0+1)*Hn) + ks*32 };
  const float4* cbw[2] = {
    (const float4*)(comb_W + (size_t)(n0+0)*(Hn+Dn)) + ks*32,
    (const float4*)(comb_W + (size_t)(n0+1)*(Hn+Dn)) + ks*32 };

  float bsum[2][4];
  #pragma unroll
  for (int c = 0; c < 2; c++)
    #pragma unroll
    for (int g = 0; g < 4; g++){
      int r = g*Hn + n0 + c;
      bsum[c][g] = bih[r] + bhh[r];
    }
  const float ab[2] = { attn_b[n0], attn_b[n0+1] };
  float cr[2] = {0.f, 0.f};

  __shared__ float red[4][12][Bsz];

  for (int l = 0; l <= Ln; l++){
    float a[2][4] = {{0,0,0,0},{0,0,0,0}};
    float aa[2] = {0,0}, ac[2] = {0,0};
    if (l >= 1){
      const float* hp = henc + ((l-1)&1)*(Hn*Bsz) + ks*128*Bsz + lane;
      #pragma unroll 4
      for (int q = 0; q < 32; q++){
        float v0 = hp[(4*q+0)*Bsz], v1 = hp[(4*q+1)*Bsz];
        float v2 = hp[(4*q+2)*Bsz], v3 = hp[(4*q+3)*Bsz];
        #pragma unroll
        for (int c = 0; c < 2; c++){
          #pragma unroll
          for (int g = 0; g < 4; g++){
            float4 W = whh[c*4+g][q];
            a[c][g] += v0*W.x + v1*W.y + v2*W.z + v3*W.w;
          }
          float4 Aw = atw[c][q];
          aa[c] += v0*Aw.x + v1*Aw.y + v2*Aw.z + v3*Aw.w;
          float4 Cw = cbw[c][q];
          ac[c] += v0*Cw.x + v1*Cw.y + v2*Cw.z + v3*Cw.w;
        }
      }
    }
    if (l < Ln){
      const float* dp = demoT + ((size_t)l*Dn + ks*32)*Bsz + lane;
      #pragma unroll
      for (int q = 0; q < 8; q++){
        float v0 = dp[(4*q+0)*Bsz], v1 = dp[(4*q+1)*Bsz];
        float v2 = dp[(4*q+2)*Bsz], v3 = dp[(4*q+3)*Bsz];
        #pragma unroll
        for (int c = 0; c < 2; c++)
          #pragma unroll
          for (int g = 0; g < 4; g++){
            float4 W = wih[c*4+g][q];
            a[c][g] += v0*W.x + v1*W.y + v2*W.z + v3*W.w;
          }
      }
    }
    #pragma unroll
    for (int c = 0; c < 2; c++){
      #pragma unroll
      for (int g = 0; g < 4; g++) red[ks][c*4+g][lane] = a[c][g];
      red[ks][8+c][lane]  = aa[c];
      red[ks][10+c][lane] = ac[c];
    }
    __syncthreads();
    if (threadIdx.x < Bsz){
      int b = threadIdx.x;
      if (l < Ln){
        #pragma unroll
        for (int c = 0; c < 2; c++){
          float g0 = red[0][c*4+0][b]+red[1][c*4+0][b]+red[2][c*4+0][b]+red[3][c*4+0][b] + bsum[c][0];
          float g1 = red[0][c*4+1][b]+red[1][c*4+1][b]+red[2][c*4+1][b]+red[3][c*4+1][b] + bsum[c][1];
          float g2 = red[0][c*4+2][b]+red[1][c*4+2][b]+red[2][c*4+2][b]+red[3][c*4+2][b] + bsum[c][2];
          float g3 = red[0][c*4+3][b]+red[1][c*4+3][b]+red[2][c*4+3][b]+red[3][c*4+3][b] + bsum[c][3];
          float ii = sigf(g0), ff = sigf(g1), gg = tanhf(g2), oo = sigf(g3);
          float cn = ff*cr[c] + ii*gg;
          float hn = oo*tanhf(cn);
          cr[c] = cn;
          scst(henc + (l&1)*(Hn*Bsz) + (n0+c)*Bsz + b, hn);
        }
      }
      if (l >= 1){
        #pragma unroll
        for (int c = 0; c < 2; c++){
          float av = red[0][8+c][b]+red[1][8+c][b]+red[2][8+c][b]+red[3][8+c][b] + ab[c];
          float cv = red[0][10+c][b]+red[1][10+c][b]+red[2][10+c][b]+red[3][10+c][b];
          scst(attnp + ((size_t)(b*Ln + (l-1)))*Hn + n0 + c, av);
          scst(CE + ((size_t)(b*Hn + n0 + c))*Ln + (l-1), cv);
        }
      }
    }
    if (l < Ln) gbar(bar+0, bar+1, (int)gridDim.x, l+1);
  }
}

// ---------- persistent decoder: 256 blocks, 2 phases/step ----------
__global__ __launch_bounds__(256, 1) void dec_scan_kernel(
    const float* __restrict__ h0, const float* __restrict__ c0,
    const float* __restrict__ attnp,   // [Bsz*Ln][Hn]
    const float* __restrict__ CE,      // [Bsz*Hn][Ln]
    const float* __restrict__ preobs,  // [Tn*Bsz][Hn]
    const int*   __restrict__ dlen,
    const float* __restrict__ lstm_Wih, const float* __restrict__ lstm_Whh,
    const float* __restrict__ lstm_bih, const float* __restrict__ lstm_bhh,
    const float* __restrict__ comb_b,
    float* __restrict__ hT,            // 2 x [Hn][Bsz]
    float* __restrict__ xT,            // [Hn][Bsz]
    float* __restrict__ hhist,         // [Tn][Bsz][Hn]
    float* __restrict__ outp,
    int* __restrict__ bar)
{
  const int bid  = blockIdx.x;
  const int tid  = threadIdx.x;
  const int lane = tid & 63;
  const int ks   = tid >> 6;
  const int n0 = bid*2;

  __shared__ float hs[Hn];
  __shared__ float wls[128];
  __shared__ float mx_s, sum_s;
  __shared__ float red[4][8][Bsz];

  const float4* wi[8]; const float4* wh[8];
  #pragma unroll
  for (int c = 0; c < 2; c++)
    #pragma unroll
    for (int g = 0; g < 4; g++){
      int r = g*Hn + n0 + c;
      wi[c*4+g] = (const float4*)(lstm_Wih + (size_t)r*Hn) + ks*32;
      wh[c*4+g] = (const float4*)(lstm_Whh + (size_t)r*Hn) + ks*32;
    }
  float bs[2][4];
  #pragma unroll
  for (int c = 0; c < 2; c++)
    #pragma unroll
    for (int g = 0; g < 4; g++){
      int r = g*Hn + n0 + c;
      bs[c][g] = lstm_bih[r] + lstm_bhh[r];
    }
  float cr[2] = {0.f, 0.f};
  int ph = 0;

  for (int t = 0; t < Tn; t++){
    // ============ Phase 1: attention scores + softmax + x (blocks 0..63) ============
    if (bid < Bsz){
      const int b = bid;
      const float* hrow = (t == 0) ? (h0 + (size_t)b*Hn)
                                   : (hhist + ((size_t)(t-1)*Bsz + b)*Hn);
      for (int i = tid; i < Hn; i += 256) hs[i] = hrow[i];
      if (tid >= 200 && tid < 228) wls[tid - 100] = -1e30f;
      __syncthreads();
      const int len = dlen[b];
      if (tid < 200){
        int l = tid >> 1, kh = tid & 1;
        const float4* ap = (const float4*)(attnp + ((size_t)(b*Ln + l))*Hn + kh*256);
        const float4* hv = (const float4*)(hs + kh*256);
        float s = 0.f;
        #pragma unroll 8
        for (int k = 0; k < 64; k++){
          float4 A = ap[k], H = hv[k];
          s += A.x*H.x + A.y*H.y + A.z*H.z + A.w*H.w;
        }
        s += __shfl_xor(s, 1);
        if (kh == 0) wls[l] = (l < len) ? s*0.1f : -1e30f;
      }
      __syncthreads();
      if (tid < 64){
        float v = fmaxf(wls[tid], wls[tid+64]);
        for (int off = 1; off < 64; off <<= 1) v = fmaxf(v, __shfl_xor(v, off));
        if (tid == 0) mx_s = v;
      }
      __syncthreads();
      float mx = mx_s;
      if (tid < 64){
        float e0 = (wls[tid]    > -1e29f) ? expf(wls[tid]    - mx) : 0.f;
        float e1 = (wls[tid+64] > -1e29f) ? expf(wls[tid+64] - mx) : 0.f;
        wls[tid] = e0; wls[tid+64] = e1;
        float v = e0 + e1;
        for (int off = 1; off < 64; off <<= 1) v += __shfl_xor(v, off);
        if (tid == 0) sum_s = v;
      }
      __syncthreads();
      float inv = 1.0f / sum_s;
      const float* pr = preobs + ((size_t)(t*Bsz + b))*Hn;
      #pragma unroll
      for (int c2 = 0; c2 < 2; c2++){
        int n = tid + c2*256;
        const float* cer = CE + ((size_t)(b*Hn + n))*Ln;
        float acc = 0.f;
        for (int l2 = 0; l2 < len; ++l2) acc += cer[l2]*wls[l2];
        float v = acc*inv + pr[n] + comb_b[n];
        scst(xT + n*Bsz + b, fmaxf(v, 0.f));
      }
    }
    gbar(bar+2, bar+3, (int)gridDim.x, ++ph);

    // ============ Phase 2: gates = Wih@x + Whh@h_prev + bias; cell ============
    {
      float a[2][4] = {{0,0,0,0},{0,0,0,0}};
      const float* xp = xT + ks*128*Bsz + lane;
      #pragma unroll 4
      for (int q = 0; q < 32; q++){
        float v0 = xp[(4*q+0)*Bsz], v1 = xp[(4*q+1)*Bsz];
        float v2 = xp[(4*q+2)*Bsz], v3 = xp[(4*q+3)*Bsz];
        #pragma unroll
        for (int c = 0; c < 2; c++)
          #pragma unroll
          for (int g = 0; g < 4; g++){
            float4 W = wi[c*4+g][q];
            a[c][g] += v0*W.x + v1*W.y + v2*W.z + v3*W.w;
          }
      }
      if (t == 0){
        #pragma unroll 4
        for (int q = 0; q < 32; q++){
          int k = ks*128 + 4*q;
          float v0 = h0[(size_t)lane*Hn + k+0], v1 = h0[(size_t)lane*Hn + k+1];
          float v2 = h0[(size_t)lane*Hn + k+2], v3 = h0[(size_t)lane*Hn + k+3];
          #pragma unroll
          for (int c = 0; c < 2; c++)
            #pragma unroll
            for (int g = 0; g < 4; g++){
              float4 W = wh[c*4+g][q];
              a[c][g] += v0*W.x + v1*W.y + v2*W.z + v3*W.w;
            }
        }
      } else {
        const float* hp = hT + ((t&1)^1)*(Hn*Bsz) + ks*128*Bsz + lane;
        #pragma unroll 4
        for (int q = 0; q < 32; q++){
          float v0 = hp[(4*q+0)*Bsz], v1 = hp[(4*q+1)*Bsz];
          float v2 = hp[(4*q+2)*Bsz], v3 = hp[(4*q+3)*Bsz];
          #pragma unroll
          for (int c = 0; c < 2; c++)
            #pragma unroll
            for (int g = 0; g < 4; g++){
              float4 W = wh[c*4+g][q];
              a[c][g] += v0*W.x + v1*W.y + v2*W.z + v3*W.w;
            }
        }
      }
      #pragma unroll
      for (int c = 0; c < 2; c++)
        #pragma unroll
        for (int g = 0; g < 4; g++) red[ks][c*4+g][lane] = a[c][g];
      __syncthreads();
      if (tid < Bsz){
        int b = tid;
        #pragma unroll
        for (int c = 0; c < 2; c++){
          int n = n0 + c;
          if (t == 0) cr[c] = c0[(size_t)b*Hn + n];
          float g0 = red[0][c*4+0][b]+red[1][c*4+0][b]+red[2][c*4+0][b]+red[3][c*4+0][b] + bs[c][0];
          float g1 = red[0][c*4+1][b]+red[1][c*4+1][b]+red[2][c*4+1][b]+red[3][c*4+1][b] + bs[c][1];
          float g2 = red[0][c*4+2][b]+red[1][c*4+2][b]+red[2][c*4+2][b]+red[3][c*4+2][b] + bs[c][2];
          float g3 = red[0][c*4+3][b]+red[1][c*4+3][b]+red[2][c*4+3][b]+red[3][c*4+3][b] + bs[c][3];
          float ii = sigf(g0), ff = sigf(g1), gg = tanhf(g2), oo = sigf(g3);
          float cn = ff*cr[c] + ii*gg;
          float hn = oo*tanhf(cn);
          cr[c] = cn;
          scst(hT + (t&1)*(Hn*Bsz) + n*Bsz + b, hn);
          scst(hhist + ((size_t)t*Bsz + b)*Hn + n, hn);
          if (t == Tn - 1){
            outp[Tn*Bsz*An + (size_t)b*Hn + n]           = hn;
            outp[Tn*Bsz*An + Bsz*Hn + (size_t)b*Hn + n]  = cn;
          }
        }
      }
    }
    if (t < Tn - 1) gbar(bar+2, bar+3, (int)gridDim.x, ++ph);
  }
}

// ---------- q head ----------
__global__ __launch_bounds__(256) void qout_kernel(
    const float* __restrict__ m, const float* __restrict__ out_W,
    const float* __restrict__ out_b, float* __restrict__ q)
{
  const int t = blockIdx.x;
  for (int p = threadIdx.x; p < Bsz*An; p += 256) {
    int b = p / An, a2 = p % An;
    const float* mr = m + ((size_t)(t*Bsz + b))*Hn;
    const float* wr = out_W + (size_t)a2*Hn;
    float s = out_b[a2];
    #pragma unroll 8
    for (int k = 0; k < Hn; k++) s += mr[k]*wr[k];
    q[((size_t)(t*Bsz + b))*An + a2] = s;
  }
}

extern "C" void kernel_launch(void* const* d_in, const int* in_sizes, int n_in,
                              void* d_out, int out_size, void* d_ws, size_t ws_size,
                              hipStream_t stream) {
  (void)in_sizes; (void)n_in; (void)out_size; (void)ws_size;
  const float* state    = (const float*)d_in[0];
  const float* demo     = (const float*)d_in[1];
  const int*   dlen     = (const int*)  d_in[2];
  const float* h0       = (const float*)d_in[5];
  const float* c0       = (const float*)d_in[6];
  const float* enc_Wih  = (const float*)d_in[7];
  const float* enc_Whh  = (const float*)d_in[8];
  const float* enc_bih  = (const float*)d_in[9];
  const float* enc_bhh  = (const float*)d_in[10];
  const float* attn_W   = (const float*)d_in[11];
  const float* attn_b   = (const float*)d_in[12];
  const float* comb_W   = (const float*)d_in[13];
  const float* comb_b   = (const float*)d_in[14];
  const float* lstm_Wih = (const float*)d_in[15];
  const float* lstm_Whh = (const float*)d_in[16];
  const float* lstm_bih = (const float*)d_in[17];
  const float* lstm_bhh = (const float*)d_in[18];
  const float* mid_W    = (const float*)d_in[19];
  const float* mid_b    = (const float*)d_in[20];
  const float* out_W    = (const float*)d_in[21];
  const float* out_b    = (const float*)d_in[22];
  float* ws   = (float*)d_ws;
  float* qout = (float*)d_out;

  // workspace layout (floats)
  float* demoT  = ws + 0;         // 819200
  float* henc   = ws + 819200;    // 65536
  float* attnp  = ws + 884736;    // 3276800
  float* CE     = ws + 4161536;   // 3276800  [Bsz*Hn][Ln]
  float* preobs = ws + 7438336;   // 2097152  [Tn*Bsz][Hn]
  float* hT     = ws + 9535488;   // 65536
  float* xT     = ws + 9601024;   // 32768
  float* hhist  = ws + 9633792;   // 2097152
  int*   bar    = (int*)(ws + 11730944); // 4 ints
  float* mbuf   = CE;             // alias: CE dead after decoder

  hipMemsetAsync((void*)bar, 0, 16, stream);

  demo_transpose_kernel<<<3200, 256, 0, stream>>>(demo, demoT);

  // preobs[(t,b)][n] = state[t,b,:] . comb_W[n, 512:640]
  gemm_nt_kernel<<<dim3(Tn*Bsz/64, Hn/64), 256, 0, stream>>>(
      state, Dn, comb_W + Hn, Hn + Dn, nullptr, preobs, Hn, Dn);

  enc_scan_kernel<<<256, 256, 0, stream>>>(
      demoT, enc_Wih, enc_Whh, enc_bih, enc_bhh, attn_W, attn_b, comb_W,
      henc, attnp, CE, bar);

  dec_scan_kernel<<<256, 256, 0, stream>>>(
      h0, c0, attnp, CE, preobs, dlen, lstm_Wih, lstm_Whh, lstm_bih, lstm_bhh,
      comb_b, hT, xT, hhist, qout, bar);

  // m = hhist @ mid_W^T + mid_b
  gemm_nt_kernel<<<dim3(Tn*Bsz/64, Hn/64), 256, 0, stream>>>(
      hhist, Hn, mid_W, Hn, mid_b, mbuf, Hn, Hn);

  qout_kernel<<<Tn, 256, 0, stream>>>(mbuf, out_W, out_b, qout);
}

// Round 4
// 6523.091 us; speedup vs baseline: 5.2445x; 1.0547x over previous
//
#include <hip/hip_runtime.h>
#include <math.h>

#define Bsz 64
#define Tn 64
#define Ln 100
#define Dn 128
#define An 18
#define Hn 512

__device__ __forceinline__ float sigf(float x){ return 1.0f/(1.0f+expf(-x)); }

// write-through agent-scope store (bypasses L2; lands at coherence point)
__device__ __forceinline__ void scst(float* p, float v){
  __hip_atomic_store(p, v, __ATOMIC_RELAXED, __HIP_MEMORY_SCOPE_AGENT);
}
// agent-scope bypass load (coherent read of cross-block data, no cache inv needed)
__device__ __forceinline__ float scld(const float* p){
  return __hip_atomic_load((float*)p, __ATOMIC_RELAXED, __HIP_MEMORY_SCOPE_AGENT);
}

// grid barrier: relaxed bypass atomics only — NO cache-maintenance fences.
// s_waitcnt vmcnt(0) guarantees this block's bypass stores completed at the
// coherence point before the arrive-add; readers use bypass loads, so no
// acquire fence (and no L2 invalidation) is required.
__device__ __forceinline__ void gbar(int* arrive, int* gen, int nb, int ph){
  __syncthreads();
  if (threadIdx.x == 0){
    asm volatile("s_waitcnt vmcnt(0) lgkmcnt(0)" ::: "memory");
    int a = __hip_atomic_fetch_add(arrive, 1, __ATOMIC_RELAXED, __HIP_MEMORY_SCOPE_AGENT) + 1;
    if (a == nb*ph){
      __hip_atomic_store(gen, ph, __ATOMIC_RELAXED, __HIP_MEMORY_SCOPE_AGENT);
    } else {
      while (__hip_atomic_load(gen, __ATOMIC_RELAXED, __HIP_MEMORY_SCOPE_AGENT) < ph)
        __builtin_amdgcn_s_sleep(2);
    }
  }
  __syncthreads();
}

// ---------- demo transpose: demoT[l][d][b] = demo[0][b][l][d] ----------
__global__ __launch_bounds__(256) void demo_transpose_kernel(
    const float* __restrict__ demo, float* __restrict__ demoT)
{
  int idx = blockIdx.x*256 + threadIdx.x;
  if (idx < Ln*Dn*Bsz) {
    int b = idx & 63;
    int d = (idx >> 6) & 127;
    int l = idx >> 13;
    demoT[idx] = demo[((size_t)(b*Ln + l))*Dn + d];
  }
}

// ---------- generic tiled GEMM: C[M][N] = A[M][K] * B[N][K]^T + bias[n] ----------
__global__ __launch_bounds__(256) void gemm_nt_kernel(
    const float* __restrict__ A, int lda,
    const float* __restrict__ B, int ldb,
    const float* __restrict__ bias,
    float* __restrict__ C, int ldc, int K)
{
  __shared__ float As[64][17];
  __shared__ float Bs[64][17];
  const int m0 = blockIdx.x * 64;
  const int n0 = blockIdx.y * 64;
  const int tx = threadIdx.x & 15;
  const int ty = threadIdx.x >> 4;
  float acc[4][4] = {};
  for (int k0 = 0; k0 < K; k0 += 16) {
    #pragma unroll
    for (int i = 0; i < 4; i++) {
      int e = threadIdx.x + i*256;
      int r = e >> 4, c = e & 15;
      As[r][c] = A[(size_t)(m0 + r)*lda + k0 + c];
      Bs[r][c] = B[(size_t)(n0 + r)*ldb + k0 + c];
    }
    __syncthreads();
    #pragma unroll
    for (int kk = 0; kk < 16; kk++) {
      float a0 = As[ty*4+0][kk], a1 = As[ty*4+1][kk], a2 = As[ty*4+2][kk], a3 = As[ty*4+3][kk];
      float b0 = Bs[tx*4+0][kk], b1 = Bs[tx*4+1][kk], b2 = Bs[tx*4+2][kk], b3 = Bs[tx*4+3][kk];
      acc[0][0] += a0*b0; acc[0][1] += a0*b1; acc[0][2] += a0*b2; acc[0][3] += a0*b3;
      acc[1][0] += a1*b0; acc[1][1] += a1*b1; acc[1][2] += a1*b2; acc[1][3] += a1*b3;
      acc[2][0] += a2*b0; acc[2][1] += a2*b1; acc[2][2] += a2*b2; acc[2][3] += a2*b3;
      acc[3][0] += a3*b0; acc[3][1] += a3*b1; acc[3][2] += a3*b2; acc[3][3] += a3*b3;
    }
    __syncthreads();
  }
  #pragma unroll
  for (int i = 0; i < 4; i++) {
    #pragma unroll
    for (int j = 0; j < 4; j++) {
      int nn = n0 + tx*4 + j;
      float v = acc[i][j] + (bias ? bias[nn] : 0.0f);
      C[(size_t)(m0 + ty*4 + i)*ldc + nn] = v;
    }
  }
}

// ---------- persistent fused encoder: h-scan + attnp + CE, 256 blocks x 2 cols ----------
__global__ __launch_bounds__(256, 1) void enc_scan_kernel(
    const float* __restrict__ demoT,   // [Ln][Dn][Bsz]
    const float* __restrict__ Wih, const float* __restrict__ Whh,
    const float* __restrict__ bih, const float* __restrict__ bhh,
    const float* __restrict__ attn_W, const float* __restrict__ attn_b,
    const float* __restrict__ comb_W,
    float* __restrict__ henc,          // 2 x [Hn][Bsz]
    float* __restrict__ attnp,         // [Bsz*Ln][Hn]
    float* __restrict__ CE,            // [Bsz*Hn][Ln]
    int* __restrict__ bar)
{
  const int bid  = blockIdx.x;
  const int lane = threadIdx.x & 63;
  const int ks   = threadIdx.x >> 6;
  const int n0 = bid*2;

  const float4* whh[8]; const float4* wih[8];
  #pragma unroll
  for (int c = 0; c < 2; c++)
    #pragma unroll
    for (int g = 0; g < 4; g++){
      int r = g*Hn + n0 + c;
      whh[c*4+g] = (const float4*)(Whh + (size_t)r*Hn) + ks*32;
      wih[c*4+g] = (const float4*)(Wih + (size_t)r*Dn) + ks*8;
    }
  const float4* atw[2] = {
    (const float4*)(attn_W + (size_t)(n0+0)*Hn) + ks*32,
    (const float4*)(attn_W + (size_t)(n0+1)*Hn) + ks*32 };
  const float4* cbw[2] = {
    (const float4*)(comb_W + (size_t)(n0+0)*(Hn+Dn)) + ks*32,
    (const float4*)(comb_W + (size_t)(n0+1)*(Hn+Dn)) + ks*32 };

  float bsum[2][4];
  #pragma unroll
  for (int c = 0; c < 2; c++)
    #pragma unroll
    for (int g = 0; g < 4; g++){
      int r = g*Hn + n0 + c;
      bsum[c][g] = bih[r] + bhh[r];
    }
  const float ab[2] = { attn_b[n0], attn_b[n0+1] };
  float cr[2] = {0.f, 0.f};

  __shared__ float red[4][12][Bsz];

  for (int l = 0; l <= Ln; l++){
    float a[2][4] = {{0,0,0,0},{0,0,0,0}};
    float aa[2] = {0,0}, ac[2] = {0,0};
    if (l >= 1){
      const float* hp = henc + ((l-1)&1)*(Hn*Bsz) + ks*128*Bsz + lane;
      #pragma unroll 4
      for (int q = 0; q < 32; q++){
        float v0 = scld(hp + (4*q+0)*Bsz), v1 = scld(hp + (4*q+1)*Bsz);
        float v2 = scld(hp + (4*q+2)*Bsz), v3 = scld(hp + (4*q+3)*Bsz);
        #pragma unroll
        for (int c = 0; c < 2; c++){
          #pragma unroll
          for (int g = 0; g < 4; g++){
            float4 W = whh[c*4+g][q];
            a[c][g] += v0*W.x + v1*W.y + v2*W.z + v3*W.w;
          }
          float4 Aw = atw[c][q];
          aa[c] += v0*Aw.x + v1*Aw.y + v2*Aw.z + v3*Aw.w;
          float4 Cw = cbw[c][q];
          ac[c] += v0*Cw.x + v1*Cw.y + v2*Cw.z + v3*Cw.w;
        }
      }
    }
    if (l < Ln){
      const float* dp = demoT + ((size_t)l*Dn + ks*32)*Bsz + lane;
      #pragma unroll
      for (int q = 0; q < 8; q++){
        float v0 = dp[(4*q+0)*Bsz], v1 = dp[(4*q+1)*Bsz];
        float v2 = dp[(4*q+2)*Bsz], v3 = dp[(4*q+3)*Bsz];
        #pragma unroll
        for (int c = 0; c < 2; c++)
          #pragma unroll
          for (int g = 0; g < 4; g++){
            float4 W = wih[c*4+g][q];
            a[c][g] += v0*W.x + v1*W.y + v2*W.z + v3*W.w;
          }
      }
    }
    #pragma unroll
    for (int c = 0; c < 2; c++){
      #pragma unroll
      for (int g = 0; g < 4; g++) red[ks][c*4+g][lane] = a[c][g];
      red[ks][8+c][lane]  = aa[c];
      red[ks][10+c][lane] = ac[c];
    }
    __syncthreads();
    if (threadIdx.x < Bsz){
      int b = threadIdx.x;
      if (l < Ln){
        #pragma unroll
        for (int c = 0; c < 2; c++){
          float g0 = red[0][c*4+0][b]+red[1][c*4+0][b]+red[2][c*4+0][b]+red[3][c*4+0][b] + bsum[c][0];
          float g1 = red[0][c*4+1][b]+red[1][c*4+1][b]+red[2][c*4+1][b]+red[3][c*4+1][b] + bsum[c][1];
          float g2 = red[0][c*4+2][b]+red[1][c*4+2][b]+red[2][c*4+2][b]+red[3][c*4+2][b] + bsum[c][2];
          float g3 = red[0][c*4+3][b]+red[1][c*4+3][b]+red[2][c*4+3][b]+red[3][c*4+3][b] + bsum[c][3];
          float ii = sigf(g0), ff = sigf(g1), gg = tanhf(g2), oo = sigf(g3);
          float cn = ff*cr[c] + ii*gg;
          float hn = oo*tanhf(cn);
          cr[c] = cn;
          scst(henc + (l&1)*(Hn*Bsz) + (n0+c)*Bsz + b, hn);
        }
      }
      if (l >= 1){
        #pragma unroll
        for (int c = 0; c < 2; c++){
          float av = red[0][8+c][b]+red[1][8+c][b]+red[2][8+c][b]+red[3][8+c][b] + ab[c];
          float cv = red[0][10+c][b]+red[1][10+c][b]+red[2][10+c][b]+red[3][10+c][b];
          scst(attnp + ((size_t)(b*Ln + (l-1)))*Hn + n0 + c, av);
          scst(CE + ((size_t)(b*Hn + n0 + c))*Ln + (l-1), cv);
        }
      }
    }
    if (l < Ln) gbar(bar+0, bar+1, (int)gridDim.x, l+1);
  }
}

// ---------- persistent decoder: 256 blocks, 2 phases/step ----------
__global__ __launch_bounds__(256, 1) void dec_scan_kernel(
    const float* __restrict__ h0, const float* __restrict__ c0,
    const float* __restrict__ attnp,   // [Bsz*Ln][Hn]
    const float* __restrict__ CE,      // [Bsz*Hn][Ln]
    const float* __restrict__ preobs,  // [Tn*Bsz][Hn]
    const int*   __restrict__ dlen,
    const float* __restrict__ lstm_Wih, const float* __restrict__ lstm_Whh,
    const float* __restrict__ lstm_bih, const float* __restrict__ lstm_bhh,
    const float* __restrict__ comb_b,
    float* __restrict__ hT,            // 2 x [Hn][Bsz]
    float* __restrict__ xT,            // [Hn][Bsz]
    float* __restrict__ hhist,         // [Tn][Bsz][Hn]
    float* __restrict__ outp,
    int* __restrict__ bar)
{
  const int bid  = blockIdx.x;
  const int tid  = threadIdx.x;
  const int lane = tid & 63;
  const int ks   = tid >> 6;
  const int n0 = bid*2;

  __shared__ float hs[Hn];
  __shared__ float wls[128];
  __shared__ float mx_s, sum_s;
  __shared__ float red[4][8][Bsz];

  const float4* wi[8]; const float4* wh[8];
  #pragma unroll
  for (int c = 0; c < 2; c++)
    #pragma unroll
    for (int g = 0; g < 4; g++){
      int r = g*Hn + n0 + c;
      wi[c*4+g] = (const float4*)(lstm_Wih + (size_t)r*Hn) + ks*32;
      wh[c*4+g] = (const float4*)(lstm_Whh + (size_t)r*Hn) + ks*32;
    }
  float bs[2][4];
  #pragma unroll
  for (int c = 0; c < 2; c++)
    #pragma unroll
    for (int g = 0; g < 4; g++){
      int r = g*Hn + n0 + c;
      bs[c][g] = lstm_bih[r] + lstm_bhh[r];
    }
  float cr[2] = {0.f, 0.f};
  int ph = 0;

  for (int t = 0; t < Tn; t++){
    // ============ Phase 1: attention scores + softmax + x (blocks 0..63) ============
    if (bid < Bsz){
      const int b = bid;
      if (t == 0){
        const float* hrow = h0 + (size_t)b*Hn;
        for (int i = tid; i < Hn; i += 256) hs[i] = hrow[i];
      } else {
        const float* hrow = hhist + ((size_t)(t-1)*Bsz + b)*Hn;
        for (int i = tid; i < Hn; i += 256) hs[i] = scld(hrow + i);
      }
      if (tid >= 200 && tid < 228) wls[tid - 100] = -1e30f;
      __syncthreads();
      const int len = dlen[b];
      if (tid < 200){
        int l = tid >> 1, kh = tid & 1;
        const float4* ap = (const float4*)(attnp + ((size_t)(b*Ln + l))*Hn + kh*256);
        const float4* hv = (const float4*)(hs + kh*256);
        float s = 0.f;
        #pragma unroll 8
        for (int k = 0; k < 64; k++){
          float4 A = ap[k], H = hv[k];
          s += A.x*H.x + A.y*H.y + A.z*H.z + A.w*H.w;
        }
        s += __shfl_xor(s, 1);
        if (kh == 0) wls[l] = (l < len) ? s*0.1f : -1e30f;
      }
      __syncthreads();
      if (tid < 64){
        float v = fmaxf(wls[tid], wls[tid+64]);
        for (int off = 1; off < 64; off <<= 1) v = fmaxf(v, __shfl_xor(v, off));
        if (tid == 0) mx_s = v;
      }
      __syncthreads();
      float mx = mx_s;
      if (tid < 64){
        float e0 = (wls[tid]    > -1e29f) ? expf(wls[tid]    - mx) : 0.f;
        float e1 = (wls[tid+64] > -1e29f) ? expf(wls[tid+64] - mx) : 0.f;
        wls[tid] = e0; wls[tid+64] = e1;
        float v = e0 + e1;
        for (int off = 1; off < 64; off <<= 1) v += __shfl_xor(v, off);
        if (tid == 0) sum_s = v;
      }
      __syncthreads();
      float inv = 1.0f / sum_s;
      const float* pr = preobs + ((size_t)(t*Bsz + b))*Hn;
      #pragma unroll
      for (int c2 = 0; c2 < 2; c2++){
        int n = tid + c2*256;
        const float* cer = CE + ((size_t)(b*Hn + n))*Ln;
        float acc = 0.f;
        for (int l2 = 0; l2 < len; ++l2) acc += cer[l2]*wls[l2];
        float v = acc*inv + pr[n] + comb_b[n];
        scst(xT + n*Bsz + b, fmaxf(v, 0.f));
      }
    }
    gbar(bar+2, bar+3, (int)gridDim.x, ++ph);

    // ============ Phase 2: gates = Wih@x + Whh@h_prev + bias; cell ============
    {
      float a[2][4] = {{0,0,0,0},{0,0,0,0}};
      const float* xp = xT + ks*128*Bsz + lane;
      #pragma unroll 4
      for (int q = 0; q < 32; q++){
        float v0 = scld(xp + (4*q+0)*Bsz), v1 = scld(xp + (4*q+1)*Bsz);
        float v2 = scld(xp + (4*q+2)*Bsz), v3 = scld(xp + (4*q+3)*Bsz);
        #pragma unroll
        for (int c = 0; c < 2; c++)
          #pragma unroll
          for (int g = 0; g < 4; g++){
            float4 W = wi[c*4+g][q];
            a[c][g] += v0*W.x + v1*W.y + v2*W.z + v3*W.w;
          }
      }
      if (t == 0){
        #pragma unroll 4
        for (int q = 0; q < 32; q++){
          int k = ks*128 + 4*q;
          float v0 = h0[(size_t)lane*Hn + k+0], v1 = h0[(size_t)lane*Hn + k+1];
          float v2 = h0[(size_t)lane*Hn + k+2], v3 = h0[(size_t)lane*Hn + k+3];
          #pragma unroll
          for (int c = 0; c < 2; c++)
            #pragma unroll
            for (int g = 0; g < 4; g++){
              float4 W = wh[c*4+g][q];
              a[c][g] += v0*W.x + v1*W.y + v2*W.z + v3*W.w;
            }
        }
      } else {
        const float* hp = hT + ((t&1)^1)*(Hn*Bsz) + ks*128*Bsz + lane;
        #pragma unroll 4
        for (int q = 0; q < 32; q++){
          float v0 = scld(hp + (4*q+0)*Bsz), v1 = scld(hp + (4*q+1)*Bsz);
          float v2 = scld(hp + (4*q+2)*Bsz), v3 = scld(hp + (4*q+3)*Bsz);
          #pragma unroll
          for (int c = 0; c < 2; c++)
            #pragma unroll
            for (int g = 0; g < 4; g++){
              float4 W = wh[c*4+g][q];
              a[c][g] += v0*W.x + v1*W.y + v2*W.z + v3*W.w;
            }
        }
      }
      #pragma unroll
      for (int c = 0; c < 2; c++)
        #pragma unroll
        for (int g = 0; g < 4; g++) red[ks][c*4+g][lane] = a[c][g];
      __syncthreads();
      if (tid < Bsz){
        int b = tid;
        #pragma unroll
        for (int c = 0; c < 2; c++){
          int n = n0 + c;
          if (t == 0) cr[c] = c0[(size_t)b*Hn + n];
          float g0 = red[0][c*4+0][b]+red[1][c*4+0][b]+red[2][c*4+0][b]+red[3][c*4+0][b] + bs[c][0];
          float g1 = red[0][c*4+1][b]+red[1][c*4+1][b]+red[2][c*4+1][b]+red[3][c*4+1][b] + bs[c][1];
          float g2 = red[0][c*4+2][b]+red[1][c*4+2][b]+red[2][c*4+2][b]+red[3][c*4+2][b] + bs[c][2];
          float g3 = red[0][c*4+3][b]+red[1][c*4+3][b]+red[2][c*4+3][b]+red[3][c*4+3][b] + bs[c][3];
          float ii = sigf(g0), ff = sigf(g1), gg = tanhf(g2), oo = sigf(g3);
          float cn = ff*cr[c] + ii*gg;
          float hn = oo*tanhf(cn);
          cr[c] = cn;
          scst(hT + (t&1)*(Hn*Bsz) + n*Bsz + b, hn);
          scst(hhist + ((size_t)t*Bsz + b)*Hn + n, hn);
          if (t == Tn - 1){
            outp[Tn*Bsz*An + (size_t)b*Hn + n]           = hn;
            outp[Tn*Bsz*An + Bsz*Hn + (size_t)b*Hn + n]  = cn;
          }
        }
      }
    }
    if (t < Tn - 1) gbar(bar+2, bar+3, (int)gridDim.x, ++ph);
  }
}

// ---------- q head ----------
__global__ __launch_bounds__(256) void qout_kernel(
    const float* __restrict__ m, const float* __restrict__ out_W,
    const float* __restrict__ out_b, float* __restrict__ q)
{
  const int t = blockIdx.x;
  for (int p = threadIdx.x; p < Bsz*An; p += 256) {
    int b = p / An, a2 = p % An;
    const float* mr = m + ((size_t)(t*Bsz + b))*Hn;
    const float* wr = out_W + (size_t)a2*Hn;
    float s = out_b[a2];
    #pragma unroll 8
    for (int k = 0; k < Hn; k++) s += mr[k]*wr[k];
    q[((size_t)(t*Bsz + b))*An + a2] = s;
  }
}

extern "C" void kernel_launch(void* const* d_in, const int* in_sizes, int n_in,
                              void* d_out, int out_size, void* d_ws, size_t ws_size,
                              hipStream_t stream) {
  (void)in_sizes; (void)n_in; (void)out_size; (void)ws_size;
  const float* state    = (const float*)d_in[0];
  const float* demo     = (const float*)d_in[1];
  const int*   dlen     = (const int*)  d_in[2];
  const float* h0       = (const float*)d_in[5];
  const float* c0       = (const float*)d_in[6];
  const float* enc_Wih  = (const float*)d_in[7];
  const float* enc_Whh  = (const float*)d_in[8];
  const float* enc_bih  = (const float*)d_in[9];
  const float* enc_bhh  = (const float*)d_in[10];
  const float* attn_W   = (const float*)d_in[11];
  const float* attn_b   = (const float*)d_in[12];
  const float* comb_W   = (const float*)d_in[13];
  const float* comb_b   = (const float*)d_in[14];
  const float* lstm_Wih = (const float*)d_in[15];
  const float* lstm_Whh = (const float*)d_in[16];
  const float* lstm_bih = (const float*)d_in[17];
  const float* lstm_bhh = (const float*)d_in[18];
  const float* mid_W    = (const float*)d_in[19];
  const float* mid_b    = (const float*)d_in[20];
  const float* out_W    = (const float*)d_in[21];
  const float* out_b    = (const float*)d_in[22];
  float* ws   = (float*)d_ws;
  float* qout = (float*)d_out;

  // workspace layout (floats)
  float* demoT  = ws + 0;         // 819200
  float* henc   = ws + 819200;    // 65536
  float* attnp  = ws + 884736;    // 3276800
  float* CE     = ws + 4161536;   // 3276800  [Bsz*Hn][Ln]
  float* preobs = ws + 7438336;   // 2097152  [Tn*Bsz][Hn]
  float* hT     = ws + 9535488;   // 65536
  float* xT     = ws + 9601024;   // 32768
  float* hhist  = ws + 9633792;   // 2097152
  int*   bar    = (int*)(ws + 11730944); // 4 ints
  float* mbuf   = CE;             // alias: CE dead after decoder

  hipMemsetAsync((void*)bar, 0, 16, stream);

  demo_transpose_kernel<<<3200, 256, 0, stream>>>(demo, demoT);

  // preobs[(t,b)][n] = state[t,b,:] . comb_W[n, 512:640]
  gemm_nt_kernel<<<dim3(Tn*Bsz/64, Hn/64), 256, 0, stream>>>(
      state, Dn, comb_W + Hn, Hn + Dn, nullptr, preobs, Hn, Dn);

  enc_scan_kernel<<<256, 256, 0, stream>>>(
      demoT, enc_Wih, enc_Whh, enc_bih, enc_bhh, attn_W, attn_b, comb_W,
      henc, attnp, CE, bar);

  dec_scan_kernel<<<256, 256, 0, stream>>>(
      h0, c0, attnp, CE, preobs, dlen, lstm_Wih, lstm_Whh, lstm_bih, lstm_bhh,
      comb_b, hT, xT, hhist, qout, bar);

  // m = hhist @ mid_W^T + mid_b
  gemm_nt_kernel<<<dim3(Tn*Bsz/64, Hn/64), 256, 0, stream>>>(
      hhist, Hn, mid_W, Hn, mid_b, mbuf, Hn, Hn);

  qout_kernel<<<Tn, 256, 0, stream>>>(mbuf, out_W, out_b, qout);
}